// Round 1
// baseline (469.836 us; speedup 1.0000x reference)
//
#include <hip/hip_runtime.h>
#include <stdint.h>

// Problem constants
#define B_ 32
#define N_ 2048
#define D_ 1024
#define H_ 16

typedef __attribute__((ext_vector_type(8))) short short8;
typedef __attribute__((ext_vector_type(4))) float f32x4;

__device__ __forceinline__ unsigned short f2bf(float x) {
    unsigned u = __float_as_uint(x);
    u += 0x7FFFu + ((u >> 16) & 1u);   // RNE
    return (unsigned short)(u >> 16);
}
__device__ __forceinline__ float bfhi(unsigned u) { return __uint_as_float(u & 0xFFFF0000u); }
__device__ __forceinline__ float bflo(unsigned u) { return __uint_as_float(u << 16); }

// ---------------------------------------------------------------------------
// Generic coalesced wave-GEMV: out_row[j] = dot(W[j,:1024], vec) + bias[j]
// vec = vec_base + (bx/vdiv)*1024 ; out_row = out + (bx/mod)*1024 ;
// j in [(bx%mod)*nout, +nout)
// ---------------------------------------------------------------------------
__global__ __launch_bounds__(256) void gemv_k(const float* __restrict__ vec_base, int vdiv,
        const float* __restrict__ W, const float* __restrict__ bias,
        float* __restrict__ out, int nout, int mod) {
    __shared__ float vlds[1024];
    int bx = blockIdx.x, t = threadIdx.x;
    const float* vec = vec_base + (size_t)(bx / vdiv) * 1024;
    float* orow = out + (size_t)(bx / mod) * 1024;
    int j0 = (bx % mod) * nout;
    *(float4*)&vlds[4 * t] = *(const float4*)&vec[4 * t];
    __syncthreads();
    int w = t >> 6, l = t & 63;
    int per = nout >> 2;           // outputs per wave
    for (int s = 0; s < per; s++) {
        int j = j0 + w * per + s;
        const float4* Wr = (const float4*)(W + (size_t)j * 1024);
        float acc = 0.f;
        #pragma unroll
        for (int kk = 0; kk < 4; kk++) {
            float4 a = Wr[kk * 64 + l];
            float4 v = *(const float4*)&vlds[(kk * 64 + l) * 4];
            acc += a.x * v.x + a.y * v.y + a.z * v.z + a.w * v.w;
        }
        #pragma unroll
        for (int m = 32; m >= 1; m >>= 1) acc += __shfl_xor(acc, m, 64);
        if (l == 0) orow[j] = acc + bias[j];
    }
}

// ---------------------------------------------------------------------------
// Prep: blocks 0..15  -> R[h,d] = 0.125 * sum_j q[64h+j]*w_k[64h+j, d],
//                        stored as bf16 MFMA A-fragments rAf[i][lane][8]
//        blocks 16..47 -> any_ws[b] = OR over mask row b
// ---------------------------------------------------------------------------
__global__ __launch_bounds__(256) void prep_k(const float* __restrict__ q,
        const float* __restrict__ wk, const int* __restrict__ mask,
        unsigned short* __restrict__ rAf, int* __restrict__ any_ws) {
    __shared__ float qh[64];
    __shared__ int wf[4];
    int bx = blockIdx.x, t = threadIdx.x;
    if (bx < 16) {
        int h = bx;
        if (t < 64) qh[t] = q[h * 64 + t];
        __syncthreads();
        float4 acc = make_float4(0.f, 0.f, 0.f, 0.f);
        const float4* wk4 = (const float4*)wk;
        for (int j = 0; j < 64; j++) {
            float qv = qh[j];
            float4 wv = wk4[(size_t)(h * 64 + j) * 256 + t];
            acc.x += qv * wv.x; acc.y += qv * wv.y;
            acc.z += qv * wv.z; acc.w += qv * wv.w;
        }
        const float scale = 0.125f;    // 1/sqrt(64), folded into R
        float av[4] = {acc.x * scale, acc.y * scale, acc.z * scale, acc.w * scale};
        #pragma unroll
        for (int dd = 0; dd < 4; dd++) {
            int d = 4 * t + dd;
            int i = d >> 5, g = (d >> 3) & 3, jj = d & 7;
            int lane = (g << 4) | h;   // A[m=lane&15][k=(lane>>4)*8+j]
            rAf[(size_t)(i * 64 + lane) * 8 + jj] = f2bf(av[dd]);
        }
    } else {
        int b = bx - 16;
        int v = 0;
        for (int k = 0; k < 8; k++) v |= mask[b * N_ + k * 256 + t];
        unsigned long long bal = __ballot(v != 0);
        int w = t >> 6;
        if ((t & 63) == 0) wf[w] = (bal != 0ull) ? 1 : 0;
        __syncthreads();
        if (t == 0) any_ws[b] = wf[0] | wf[1] | wf[2] | wf[3];
    }
}

// ---------------------------------------------------------------------------
// Main streaming kernel. grid = 1024 (b = bx>>5, chunk c = bx&31, 64 rows).
// Per 16-row iteration: stage z tile (bf16, LDS) -> S^T via MFMA ->
// e = mask ? exp(s) : 0 -> ctx[h][4d] register accumulation.
// Writes per-chunk partial ctx (bf16) and l (f32) to workspace.
// ---------------------------------------------------------------------------
__global__ __launch_bounds__(256, 2) void main_k(const float* __restrict__ z,
        const int* __restrict__ mask, const int* __restrict__ any_ws,
        const unsigned short* __restrict__ rAf,
        unsigned short* __restrict__ ctx_ws, float* __restrict__ l_ws) {
    __shared__ unsigned short zt[16][1024];   // 32 KB bf16 tile, row-major
    __shared__ float Cpart[4][16][16];        // per-wave K-partial C tiles
    __shared__ float E_lds[256];              // e[n][h]
    __shared__ float lred[256];
    int bx = blockIdx.x, t = threadIdx.x;
    int b = bx >> 5, c = bx & 31;
    int n0 = c * 64;
    int w = t >> 6, l = t & 63;
    int frow = l & 15, fquad = l >> 4;        // MFMA fragment coords
    int eh = t & 15, en = t >> 4;             // (h, n) for E phase
    int anyb = any_ws[b];
    const float4* zg4 = (const float4*)(z + (size_t)b * N_ * D_);
    const short8* rA8 = (const short8*)rAf;
    float4 ctx[16];
    #pragma unroll
    for (int h = 0; h < 16; h++) ctx[h] = make_float4(0.f, 0.f, 0.f, 0.f);
    float l_acc = 0.f;

    for (int it = 0; it < 4; it++) {
        int rbase = n0 + it * 16;
        // --- stage 16 rows of z as bf16 into LDS (coalesced float4 reads) ---
        #pragma unroll
        for (int k = 0; k < 16; k++) {
            float4 v = zg4[(size_t)(rbase + k) * 256 + t];
            ushort4 o;
            o.x = f2bf(v.x); o.y = f2bf(v.y); o.z = f2bf(v.z); o.w = f2bf(v.w);
            *(ushort4*)&zt[k][4 * t] = o;
        }
        __syncthreads();
        // --- scores: wave w covers d in [256w, 256w+256), 8 MFMAs ---
        f32x4 acc = {0.f, 0.f, 0.f, 0.f};
        #pragma unroll
        for (int ib = 0; ib < 8; ib++) {
            int i = w * 8 + ib;
            short8 af = rA8[i * 64 + l];                              // A = R (L1-hot)
            short8 bf = *(const short8*)&zt[frow][i * 32 + fquad * 8]; // B = z rows
            acc = __builtin_amdgcn_mfma_f32_16x16x32_bf16(af, bf, acc, 0, 0, 0);
        }
        #pragma unroll
        for (int r = 0; r < 4; r++) Cpart[w][fquad * 4 + r][frow] = acc[r];
        __syncthreads();
        // --- E = masked exp(s) (scores are O(0.1): no max-subtraction needed) ---
        {
            float s = Cpart[0][eh][en] + Cpart[1][eh][en]
                    + Cpart[2][eh][en] + Cpart[3][eh][en];
            int gn = rbase + en;
            bool valid = (mask[b * N_ + gn] != 0) || (gn == 0 && anyb == 0);
            float e = valid ? __expf(s) : 0.f;
            E_lds[t] = e;      // index == en*16+eh
            l_acc += e;
        }
        __syncthreads();
        // --- ctx accumulation: thread owns d = [4t,4t+4), all 16 heads ---
        for (int r = 0; r < 16; r++) {
            float er[16];
            *(float4*)&er[0]  = *(const float4*)&E_lds[r * 16 + 0];
            *(float4*)&er[4]  = *(const float4*)&E_lds[r * 16 + 4];
            *(float4*)&er[8]  = *(const float4*)&E_lds[r * 16 + 8];
            *(float4*)&er[12] = *(const float4*)&E_lds[r * 16 + 12];
            uint2 p = *(const uint2*)&zt[r][4 * t];
            float z0 = bflo(p.x), z1 = bfhi(p.x), z2 = bflo(p.y), z3 = bfhi(p.y);
            #pragma unroll
            for (int h = 0; h < 16; h++) {
                float e = er[h];
                ctx[h].x += e * z0; ctx[h].y += e * z1;
                ctx[h].z += e * z2; ctx[h].w += e * z3;
            }
        }
        __syncthreads();
    }
    // --- write per-chunk partials ---
    #pragma unroll
    for (int h = 0; h < 16; h++) {
        ushort4 o;
        o.x = f2bf(ctx[h].x); o.y = f2bf(ctx[h].y);
        o.z = f2bf(ctx[h].z); o.w = f2bf(ctx[h].w);
        *(ushort4*)&ctx_ws[((size_t)bx * 16 + h) * 1024 + 4 * t] = o;
    }
    lred[t] = l_acc;
    __syncthreads();
    if (t < 16) {
        float s = 0.f;
        #pragma unroll
        for (int ss = 0; ss < 16; ss++) s += lred[ss * 16 + t];
        l_ws[bx * 16 + t] = s;
    }
}

// ---------------------------------------------------------------------------
// Reduce partials: ctxsum[b][h][d] = (sum_c ctx)/(sum_c l), with all-masked
// fallback to z[b,0,:] (reference forces key 0 valid when row is all-false).
// ---------------------------------------------------------------------------
__global__ __launch_bounds__(256) void reduce_k(const unsigned short* __restrict__ ctx_ws,
        const float* __restrict__ l_ws, const float* __restrict__ z,
        float* __restrict__ ctxsum) {
    int o = blockIdx.x * 256 + threadIdx.x;   // 32*16*1024 outputs
    int b = o >> 14, h = (o >> 10) & 15, d = o & 1023;
    float s = 0.f, L = 0.f;
    for (int c = 0; c < 32; c++) {
        int bx = b * 32 + c;
        unsigned short us = ctx_ws[((size_t)bx * 16 + h) * 1024 + d];
        s += bflo((unsigned)us);
        L += l_ws[bx * 16 + h];
    }
    float val;
    if (L > 0.f) val = s / L;
    else         val = z[((size_t)b * N_ + 0) * D_ + d];
    ctxsum[o] = val;
}

// ---------------------------------------------------------------------------
extern "C" void kernel_launch(void* const* d_in, const int* in_sizes, int n_in,
                              void* d_out, int out_size, void* d_ws, size_t ws_size,
                              hipStream_t stream) {
    const float* z     = (const float*)d_in[0];
    const int*   mask  = (const int*)d_in[1];
    const float* query = (const float*)d_in[2];
    const float* w_q   = (const float*)d_in[3];
    const float* w_k   = (const float*)d_in[4];
    const float* w_v   = (const float*)d_in[5];
    const float* b_q   = (const float*)d_in[6];
    // d_in[7] = b_k: constant per (b,h) over n -> cancels in softmax
    const float* b_v   = (const float*)d_in[8];
    const float* w_o   = (const float*)d_in[9];
    const float* b_o   = (const float*)d_in[10];
    float* out = (float*)d_out;

    char* ws = (char*)d_ws;
    float*          q_ws   = (float*)(ws + 0);            //  4 KB
    int*            any_ws = (int*)(ws + 4096);           //  128 B
    unsigned short* rAf    = (unsigned short*)(ws + 8192);//  32 KB
    float*          l_ws   = (float*)(ws + 40960);        //  64 KB
    float*          ctxsum = (float*)(ws + 131072);       //  2 MB
    float*          pooled = (float*)(ws + 2228224);      //  128 KB
    unsigned short* ctx_ws = (unsigned short*)(ws + 4194304); // 32 MB

    // q = query @ w_q.T + b_q   (vec=query, 64 blocks x 16 outputs)
    gemv_k<<<64, 256, 0, stream>>>(query, 64, w_q, b_q, q_ws, 16, 64);
    // R fragments + per-batch any-valid flags
    prep_k<<<48, 256, 0, stream>>>(q_ws, w_k, mask, rAf, any_ws);
    // streaming attention pass over z
    main_k<<<1024, 256, 0, stream>>>(z, mask, any_ws, rAf, ctx_ws, l_ws);
    // combine chunk partials -> normalized context vectors
    reduce_k<<<2048, 256, 0, stream>>>(ctx_ws, l_ws, z, ctxsum);
    // pooled[b][d'] = dot(w_v[d'], ctxsum[b][d'/64]) + b_v
    gemv_k<<<512, 256, 0, stream>>>(ctxsum, 1, w_v, b_v, pooled, 64, 16);
    // out[b][j] = dot(w_o[j], pooled[b]) + b_o
    gemv_k<<<512, 256, 0, stream>>>(pooled, 16, w_o, b_o, out, 64, 16);
}